// Round 6
// baseline (379.189 us; speedup 1.0000x reference)
//
#include <hip/hip_runtime.h>
#include <stdint.h>

#define NH 12
#define HD64 64
#define SEQ 1025
#define M_ROWS (16 * SEQ)   // 16400
#define DIM 768
#define NPAD 1088           // 17 * 64, keeps V^T rows 16B-aligned

typedef __attribute__((ext_vector_type(8))) short bf16x8;
typedef __attribute__((ext_vector_type(4))) float f32x4;
typedef __attribute__((ext_vector_type(4))) short s16x4;

#define VMCNT(n) asm volatile("s_waitcnt vmcnt(" #n ")" ::: "memory")

__device__ __forceinline__ short f2bf_rne(float f) {
    union { float f; uint32_t u; } c; c.f = f;
    uint32_t u = c.u + 0x7fffu + ((c.u >> 16) & 1u);
    return (short)(u >> 16);
}

__device__ __forceinline__ int cvt_pk_bf16(float lo, float hi) {
    int r;
    asm("v_cvt_pk_bf16_f32 %0, %1, %2" : "=v"(r) : "v"(lo), "v"(hi));
    return r;
}

__device__ __forceinline__ void gload_lds16(const void* g, void* l) {
    __builtin_amdgcn_global_load_lds(
        (const __attribute__((address_space(1))) void*)g,
        (__attribute__((address_space(3))) void*)l, 16, 0, 0);
}

// T1: XCD-chunked bijective swizzle (m204).
__device__ __forceinline__ int xcd_chunk_swizzle(int orig, int nwg) {
    int q = nwg >> 3, r = nwg & 7;
    int xcd = orig & 7, i = orig >> 3;
    int start = (xcd < r) ? xcd * (q + 1) : r * (q + 1) + (xcd - r) * q;
    return start + i;
}

// ---------------- fp32 -> bf16 conversion (merged, one launch) ----------------
__global__ void f2bf3_kernel(const float* __restrict__ a, short* __restrict__ ao, int na4,
                             const float* __restrict__ b, short* __restrict__ bo, int nb4,
                             const float* __restrict__ c, short* __restrict__ co, int nc4) {
    int i = blockIdx.x * blockDim.x + threadIdx.x;
    const float* src; short* dst; int idx;
    if (i < na4) { src = a; dst = ao; idx = i; }
    else if (i < na4 + nb4) { src = b; dst = bo; idx = i - na4; }
    else if (i < na4 + nb4 + nc4) { src = c; dst = co; idx = i - na4 - nb4; }
    else return;
    f32x4 f = ((const f32x4*)src)[idx];
    s16x4 o;
    o[0] = f2bf_rne(f[0]); o[1] = f2bf_rne(f[1]);
    o[2] = f2bf_rne(f[2]); o[3] = f2bf_rne(f[3]);
    ((s16x4*)dst)[idx] = o;
}

// ============ 256x256 tile GEMM core, BK=32, 8 waves, 4-buf lead-3 ============
// LDS layout per K-tile: [256 rows][4 blocks of 8 bf16], block swizzled:
//   LDS[r][b] holds global col-block g = b ^ (r&3) ^ ((r>>2)&1)  (2-way-free reads)
// Staging slot c in [0,1024): r=c>>2, b=c&3; dest linear c*16B, source block
//   g(c) = (c&3) ^ ((c>>2)&3) ^ ((c>>4)&1).  4 gload_lds / thread / K-step.
// Pipeline: lead-3 (tiles t,t+1,t+2 in flight), vmcnt(8) steady, 1 barrier/step.

// ---------------- QKV GEMM + RoPE epilogue ----------------
__global__ __launch_bounds__(512) void qkv_gemm_kernel(
    const short* __restrict__ xb, const short* __restrict__ wb,
    const float* __restrict__ fcos, const float* __restrict__ fsin,
    short* __restrict__ Qb, short* __restrict__ Kb, short* __restrict__ VTb)
{
    __shared__ short Alds[4][256 * 32];
    __shared__ short Blds[4][256 * 32];
    const int tid = threadIdx.x;
    const int lane = tid & 63, w = tid >> 6;
    const int wm = w >> 2, wn = w & 3;          // 2 x 4 wave grid
    const int lr = lane & 15, lg = lane >> 4;
    const int tile = xcd_chunk_swizzle(blockIdx.x, 65 * 9);
    const int mt = tile / 9, nt = tile - (tile / 9) * 9;

    const int c0 = tid, c1 = tid + 512;
    int ra0 = mt * 256 + (c0 >> 2); if (ra0 > M_ROWS - 1) ra0 = M_ROWS - 1;
    int ra1 = mt * 256 + (c1 >> 2); if (ra1 > M_ROWS - 1) ra1 = M_ROWS - 1;
    const int g0 = (c0 & 3) ^ ((c0 >> 2) & 3) ^ ((c0 >> 4) & 1);
    const int g1 = (c1 & 3) ^ ((c1 >> 2) & 3) ^ ((c1 >> 4) & 1);
    const short* gA0 = xb + (size_t)ra0 * DIM + g0 * 8;
    const short* gA1 = xb + (size_t)ra1 * DIM + g1 * 8;
    const short* gB0 = wb + (size_t)(nt * 256 + (c0 >> 2)) * DIM + g0 * 8;   // < 2304
    const short* gB1 = wb + (size_t)(nt * 256 + (c1 >> 2)) * DIM + g1 * 8;
    short* lA0 = &Alds[0][0] + c0 * 8;
    short* lA1 = &Alds[0][0] + c1 * 8;
    short* lB0 = &Blds[0][0] + c0 * 8;
    short* lB1 = &Blds[0][0] + c1 * 8;

    auto stage = [&](int buf, int kt) {
        const int ko = kt * 32;
        const int lo = buf * (256 * 32);
        gload_lds16(gA0 + ko, lA0 + lo);
        gload_lds16(gA1 + ko, lA1 + lo);
        gload_lds16(gB0 + ko, lB0 + lo);
        gload_lds16(gB1 + ko, lB1 + lo);
    };

    f32x4 acc[8][4];
#pragma unroll
    for (int i = 0; i < 8; i++)
#pragma unroll
        for (int j = 0; j < 4; j++) acc[i][j] = (f32x4)0.0f;

    stage(0, 0); stage(1, 1); stage(2, 2);

    const int ablk = (lg ^ (lr & 3) ^ ((lr >> 2) & 1)) * 8;   // swizzled block addr

    for (int t = 0; t < 24; ++t) {
        if (t < 22) { VMCNT(8); } else if (t == 22) { VMCNT(4); } else { VMCNT(0); }
        __builtin_amdgcn_s_barrier();

        const short* Ab = &Alds[0][0] + (t & 3) * (256 * 32);
        const short* Bb = &Blds[0][0] + (t & 3) * (256 * 32);

        if (t < 21) stage((t + 3) & 3, t + 3);   // issue prefetch first (max lead)

        bf16x8 bF[4], aF[8];
#pragma unroll
        for (int ni = 0; ni < 4; ni++)
            bF[ni] = *(const bf16x8*)&Bb[(wn * 64 + ni * 16 + lr) * 32 + ablk];
#pragma unroll
        for (int mi = 0; mi < 8; mi++)
            aF[mi] = *(const bf16x8*)&Ab[(wm * 128 + mi * 16 + lr) * 32 + ablk];

        __builtin_amdgcn_s_setprio(1);
#pragma unroll
        for (int mi = 0; mi < 8; mi++)
#pragma unroll
            for (int ni = 0; ni < 4; ni++)
                acc[mi][ni] = __builtin_amdgcn_mfma_f32_16x16x32_bf16(aF[mi], bF[ni], acc[mi][ni], 0, 0, 0);
        __builtin_amdgcn_s_setprio(0);
    }

    // epilogue: RoPE (pairs are adjacent cols = lane^1), scale Q, scatter
#pragma unroll
    for (int mi = 0; mi < 8; mi++) {
        int mbase = mt * 256 + wm * 128 + mi * 16 + lg * 4;
#pragma unroll
        for (int j = 0; j < 4; j++) {
            int m = mbase + j;
            bool valid = (m < M_ROWS);
            int mm = valid ? m : 0;
            int b = mm / SEQ;
            int n = mm - b * SEQ;
#pragma unroll
            for (int ni = 0; ni < 4; ni++) {
                int e = nt * 256 + wn * 64 + ni * 16 + lr;
                int qkv = e / DIM;
                int rem = e - qkv * DIM;
                int h = rem >> 6, d = rem & 63;
                float v = acc[mi][ni][j];
                float vo = __shfl_xor(v, 1);       // partner col e^1 (uniform exec)
                float outv = v;
                if (qkv < 2 && n > 0) {
                    float cs = fcos[(n - 1) * 32 + (d >> 1)];
                    float sn = fsin[(n - 1) * 32 + (d >> 1)];
                    outv = (d & 1) ? (vo * sn + v * cs) : (v * cs - vo * sn);
                }
                if (qkv == 0) outv *= 0.180336881f;   // 1/sqrt(64) * log2(e)
                if (valid) {
                    short bv = f2bf_rne(outv);
                    size_t bh = (size_t)b * NH + h;
                    if (qkv == 0)      Qb[(bh * SEQ + n) * HD64 + d] = bv;
                    else if (qkv == 1) Kb[(bh * SEQ + n) * HD64 + d] = bv;
                    else               VTb[(bh * HD64 + d) * NPAD + n] = bv;
                }
            }
        }
    }
}

// ---------------- flash attention ----------------
// (round-3 structure + T5 setprio around MFMA clusters)
__global__ __launch_bounds__(256) void attn_kernel(
    const short* __restrict__ Qb, const short* __restrict__ Kb,
    const short* __restrict__ VTb, short* __restrict__ AO)
{
    __shared__ short Klds[2][64 * 64];
    __shared__ short Vlds[2][64 * 64];
    __shared__ int Plds[4][16 * 32];   // per-wave P exchange: [q=lr][32 key-pair dwords]
    const int tid = threadIdx.x;
    const int lane = tid & 63, w = tid >> 6;
    const int lr = lane & 15, lg = lane >> 4;
    const int tile = xcd_chunk_swizzle(blockIdx.x, 17 * 192);
    const int bh = tile / 17, qt = tile - (tile / 17) * 17;
    const int b = bh / NH, h = bh - b * NH;

    const short* Qp = Qb + (size_t)bh * SEQ * HD64;
    const short* Kp = Kb + (size_t)bh * SEQ * HD64;
    const short* Vp = VTb + (size_t)bh * HD64 * NPAD;

    int qr = qt * 64 + w * 16 + lr; if (qr > SEQ - 1) qr = SEQ - 1;
    bf16x8 qf0 = *(const bf16x8*)&Qp[(size_t)qr * HD64 + 0 + lg * 8];
    bf16x8 qf1 = *(const bf16x8*)&Qp[(size_t)qr * HD64 + 32 + lg * 8];

    float m_i = -1e30f, l_i = 0.f;      // per-lane scalars, q = lr
    f32x4 acc[4];
#pragma unroll
    for (int vt = 0; vt < 4; vt++) acc[vt] = (f32x4)0.0f;

    int* pw = &Plds[w][0];
    const int pswz = (lr & 3) << 3;     // xor-swizzle on key-pair index (bits 3,4)

    auto stageKV = [&](int buf, int t) {
        int k0 = t * 64;
#pragma unroll
        for (int i = 0; i < 2; i++) {
            int c = i * 256 + tid;
            int row = c >> 3, ccd = c & 7;
            int cl = ccd ^ (row & 7);
            int krow = k0 + row; if (krow > SEQ - 1) krow = SEQ - 1;
            gload_lds16(Kp + (size_t)krow * HD64 + cl * 8, &Klds[buf][c * 8]);
            gload_lds16(Vp + (size_t)row * NPAD + k0 + cl * 8, &Vlds[buf][c * 8]);
        }
    };

    stageKV(0, 0);
    asm volatile("s_waitcnt vmcnt(0)" ::: "memory");
    __syncthreads();

    for (int t = 0; t < 17; ++t) {
        int cur = t & 1;
        if (t < 16) stageKV(cur ^ 1, t + 1);   // prefetch next K/V under compute

        // swapped QK^T: s[k16] rows = key = k16*16 + lg*4 + j, col q = lr
        f32x4 s[4];
        __builtin_amdgcn_s_setprio(1);
#pragma unroll
        for (int k16 = 0; k16 < 4; k16++) {
            int krow = k16 * 16 + lr;   // A-frag row this lane LOADS
            bf16x8 kf0 = *(const bf16x8*)&Klds[cur][krow * 64 + ((0 + lg) ^ (krow & 7)) * 8];
            bf16x8 kf1 = *(const bf16x8*)&Klds[cur][krow * 64 + ((4 + lg) ^ (krow & 7)) * 8];
            f32x4 d = (f32x4)0.0f;
            d = __builtin_amdgcn_mfma_f32_16x16x32_bf16(kf0, qf0, d, 0, 0, 0);
            d = __builtin_amdgcn_mfma_f32_16x16x32_bf16(kf1, qf1, d, 0, 0, 0);
            s[k16] = d;
        }
        __builtin_amdgcn_s_setprio(0);
        if (t == 16) {
            // only key 1024 (k16==0, lg==0, j==0) is valid
            s[0][0] = (lg == 0) ? s[0][0] : -1e30f;
            s[0][1] = -1e30f; s[0][2] = -1e30f; s[0][3] = -1e30f;
#pragma unroll
            for (int k16 = 1; k16 < 4; k16++) { s[k16][0] = -1e30f; s[k16][1] = -1e30f; s[k16][2] = -1e30f; s[k16][3] = -1e30f; }
        }

        // local max tree over 16 values
        float a0 = fmaxf(s[0][0], s[0][1]), a1 = fmaxf(s[0][2], s[0][3]);
        float a2 = fmaxf(s[1][0], s[1][1]), a3 = fmaxf(s[1][2], s[1][3]);
        float a4 = fmaxf(s[2][0], s[2][1]), a5 = fmaxf(s[2][2], s[2][3]);
        float a6 = fmaxf(s[3][0], s[3][1]), a7 = fmaxf(s[3][2], s[3][3]);
        float b0 = fmaxf(fmaxf(a0, a1), fmaxf(a2, a3));
        float b1 = fmaxf(fmaxf(a4, a5), fmaxf(a6, a7));
        float pmax = fmaxf(b0, b1);
        pmax = fmaxf(pmax, __shfl_xor(pmax, 16));
        pmax = fmaxf(pmax, __shfl_xor(pmax, 32));

        // defer-max (T13): rescale only if some row grew past threshold (exp2 units)
        if (__any(pmax > m_i + 11.54f)) {
            float mnew = fmaxf(m_i, pmax);
            float sc = exp2f(m_i - mnew);
            m_i = mnew;
            l_i *= sc;
#pragma unroll
            for (int j = 0; j < 4; j++) {
                float scj = __shfl(sc, 4 * lg + j);   // sc for q = 4*lg+j lives at lane q
#pragma unroll
                for (int vt = 0; vt < 4; vt++) acc[vt][j] *= scj;
            }
        }

        // P = exp2(s - m), packed to bf16 pairs, rowsum
#pragma unroll
        for (int k16 = 0; k16 < 4; k16++) {
#pragma unroll
            for (int j = 0; j < 4; j++) s[k16][j] = exp2f(s[k16][j] - m_i);
        }
        float r0 = (s[0][0] + s[0][1]) + (s[0][2] + s[0][3]);
        float r1 = (s[1][0] + s[1][1]) + (s[1][2] + s[1][3]);
        float r2 = (s[2][0] + s[2][1]) + (s[2][2] + s[2][3]);
        float r3 = (s[3][0] + s[3][1]) + (s[3][2] + s[3][3]);
        float rowsum = (r0 + r1) + (r2 + r3);
        rowsum += __shfl_xor(rowsum, 16);
        rowsum += __shfl_xor(rowsum, 32);
        l_i += rowsum;

        // exchange P[key][q] -> A-frag P[q][key] via per-wave swizzled LDS
#pragma unroll
        for (int k16 = 0; k16 < 4; k16++) {
            int pk0 = cvt_pk_bf16(s[k16][0], s[k16][1]);
            int pk1 = cvt_pk_bf16(s[k16][2], s[k16][3]);
            int pbase = 8 * k16 + 2 * lg;
            pw[lr * 32 + ((pbase + 0) ^ pswz)] = pk0;
            pw[lr * 32 + ((pbase + 1) ^ pswz)] = pk1;
        }
        bf16x8 pa0 = *(const bf16x8*)&pw[lr * 32 + ((4 * lg) ^ pswz)];        // keys 0..31
        bf16x8 pa1 = *(const bf16x8*)&pw[lr * 32 + ((16 + 4 * lg) ^ pswz)];   // keys 32..63

        __builtin_amdgcn_s_setprio(1);
#pragma unroll
        for (int vt = 0; vt < 4; vt++) {
            int dr = vt * 16 + lr;
            bf16x8 vf0 = *(const bf16x8*)&Vlds[cur][dr * 64 + ((0 + lg) ^ (dr & 7)) * 8];
            bf16x8 vf1 = *(const bf16x8*)&Vlds[cur][dr * 64 + ((4 + lg) ^ (dr & 7)) * 8];
            acc[vt] = __builtin_amdgcn_mfma_f32_16x16x32_bf16(pa0, vf0, acc[vt], 0, 0, 0);
            acc[vt] = __builtin_amdgcn_mfma_f32_16x16x32_bf16(pa1, vf1, acc[vt], 0, 0, 0);
        }
        __builtin_amdgcn_s_setprio(0);

        asm volatile("s_waitcnt vmcnt(0)" ::: "memory");
        __syncthreads();
    }

    // store attn out: [b*1025+q][h*64 + d] bf16; gather l for q = lg*4+j
    float inv[4];
#pragma unroll
    for (int j = 0; j < 4; j++) inv[j] = 1.0f / __shfl(l_i, 4 * lg + j);
#pragma unroll
    for (int vt = 0; vt < 4; vt++) {
#pragma unroll
        for (int j = 0; j < 4; j++) {
            int qrow = qt * 64 + w * 16 + lg * 4 + j;
            if (qrow < SEQ) {
                AO[((size_t)(b * SEQ + qrow)) * DIM + h * HD64 + vt * 16 + lr] =
                    f2bf_rne(acc[vt][j] * inv[j]);
            }
        }
    }
}

// ---------------- output projection GEMM + bias ----------------
__global__ __launch_bounds__(512) void proj_gemm_kernel(
    const short* __restrict__ ab, const short* __restrict__ wb,
    const float* __restrict__ bias, float* __restrict__ out)
{
    __shared__ short Alds[4][256 * 32];
    __shared__ short Blds[4][256 * 32];
    const int tid = threadIdx.x;
    const int lane = tid & 63, w = tid >> 6;
    const int wm = w >> 2, wn = w & 3;
    const int lr = lane & 15, lg = lane >> 4;
    const int tile = xcd_chunk_swizzle(blockIdx.x, 65 * 3);
    const int mt = tile / 3, nt = tile - (tile / 3) * 3;

    const int c0 = tid, c1 = tid + 512;
    int ra0 = mt * 256 + (c0 >> 2); if (ra0 > M_ROWS - 1) ra0 = M_ROWS - 1;
    int ra1 = mt * 256 + (c1 >> 2); if (ra1 > M_ROWS - 1) ra1 = M_ROWS - 1;
    const int g0 = (c0 & 3) ^ ((c0 >> 2) & 3) ^ ((c0 >> 4) & 1);
    const int g1 = (c1 & 3) ^ ((c1 >> 2) & 3) ^ ((c1 >> 4) & 1);
    const short* gA0 = ab + (size_t)ra0 * DIM + g0 * 8;
    const short* gA1 = ab + (size_t)ra1 * DIM + g1 * 8;
    const short* gB0 = wb + (size_t)(nt * 256 + (c0 >> 2)) * DIM + g0 * 8;   // < 768
    const short* gB1 = wb + (size_t)(nt * 256 + (c1 >> 2)) * DIM + g1 * 8;
    short* lA0 = &Alds[0][0] + c0 * 8;
    short* lA1 = &Alds[0][0] + c1 * 8;
    short* lB0 = &Blds[0][0] + c0 * 8;
    short* lB1 = &Blds[0][0] + c1 * 8;

    auto stage = [&](int buf, int kt) {
        const int ko = kt * 32;
        const int lo = buf * (256 * 32);
        gload_lds16(gA0 + ko, lA0 + lo);
        gload_lds16(gA1 + ko, lA1 + lo);
        gload_lds16(gB0 + ko, lB0 + lo);
        gload_lds16(gB1 + ko, lB1 + lo);
    };

    f32x4 acc[8][4];
#pragma unroll
    for (int i = 0; i < 8; i++)
#pragma unroll
        for (int j = 0; j < 4; j++) acc[i][j] = (f32x4)0.0f;

    stage(0, 0); stage(1, 1); stage(2, 2);

    const int ablk = (lg ^ (lr & 3) ^ ((lr >> 2) & 1)) * 8;

    for (int t = 0; t < 24; ++t) {
        if (t < 22) { VMCNT(8); } else if (t == 22) { VMCNT(4); } else { VMCNT(0); }
        __builtin_amdgcn_s_barrier();

        const short* Ab = &Alds[0][0] + (t & 3) * (256 * 32);
        const short* Bb = &Blds[0][0] + (t & 3) * (256 * 32);

        if (t < 21) stage((t + 3) & 3, t + 3);

        bf16x8 bF[4], aF[8];
#pragma unroll
        for (int ni = 0; ni < 4; ni++)
            bF[ni] = *(const bf16x8*)&Bb[(wn * 64 + ni * 16 + lr) * 32 + ablk];
#pragma unroll
        for (int mi = 0; mi < 8; mi++)
            aF[mi] = *(const bf16x8*)&Ab[(wm * 128 + mi * 16 + lr) * 32 + ablk];

        __builtin_amdgcn_s_setprio(1);
#pragma unroll
        for (int mi = 0; mi < 8; mi++)
#pragma unroll
            for (int ni = 0; ni < 4; ni++)
                acc[mi][ni] = __builtin_amdgcn_mfma_f32_16x16x32_bf16(aF[mi], bF[ni], acc[mi][ni], 0, 0, 0);
        __builtin_amdgcn_s_setprio(0);
    }

#pragma unroll
    for (int ni = 0; ni < 4; ni++) {
        int e = nt * 256 + wn * 64 + ni * 16 + lr;
        float bv = bias[e];
#pragma unroll
        for (int mi = 0; mi < 8; mi++) {
#pragma unroll
            for (int j = 0; j < 4; j++) {
                int m = mt * 256 + wm * 128 + mi * 16 + lg * 4 + j;
                if (m < M_ROWS) out[(size_t)m * DIM + e] = acc[mi][ni][j] + bv;
            }
        }
    }
}

extern "C" void kernel_launch(void* const* d_in, const int* in_sizes, int n_in,
                              void* d_out, int out_size, void* d_ws, size_t ws_size,
                              hipStream_t stream) {
    const float* x     = (const float*)d_in[0];
    const float* fcos  = (const float*)d_in[1];
    const float* fsin  = (const float*)d_in[2];
    const float* wqkv  = (const float*)d_in[3];
    const float* wproj = (const float*)d_in[4];
    const float* bproj = (const float*)d_in[5];
    float* out = (float*)d_out;

    char* ws = (char*)d_ws;
    size_t off = 0;
    auto salloc = [&](size_t bytes) { void* p = ws + off; off += (bytes + 255) & ~(size_t)255; return p; };
    short* xb     = (short*)salloc((size_t)M_ROWS * DIM * 2);
    short* wqkvb  = (short*)salloc((size_t)2304 * DIM * 2);
    short* wprojb = (short*)salloc((size_t)DIM * DIM * 2);
    short* Qb     = (short*)salloc((size_t)192 * SEQ * HD64 * 2);
    short* Kb     = (short*)salloc((size_t)192 * SEQ * HD64 * 2);
    short* VTb    = (short*)salloc((size_t)192 * HD64 * NPAD * 2);
    short* AO     = (short*)salloc((size_t)M_ROWS * DIM * 2);

    {
        int na4 = M_ROWS * DIM / 4;      // 3,148,800
        int nb4 = 2304 * DIM / 4;        //   442,368
        int nc4 = DIM * DIM / 4;         //   147,456
        int tot = na4 + nb4 + nc4;
        f2bf3_kernel<<<(tot + 255) / 256, 256, 0, stream>>>(x, xb, na4, wqkv, wqkvb, nb4, wproj, wprojb, nc4);
    }

    qkv_gemm_kernel<<<65 * 9, 512, 0, stream>>>(xb, wqkvb, fcos, fsin, Qb, Kb, VTb);
    attn_kernel<<<17 * 192, 256, 0, stream>>>(Qb, Kb, VTb, AO);
    proj_gemm_kernel<<<65 * 3, 512, 0, stream>>>(AO, wprojb, bproj, out);
}

// Round 7
// 350.530 us; speedup vs baseline: 1.0818x; 1.0818x over previous
//
#include <hip/hip_runtime.h>
#include <stdint.h>

#define NH 12
#define HD64 64
#define SEQ 1025
#define M_ROWS (16 * SEQ)   // 16400
#define DIM 768
#define NPAD 1088           // 17 * 64, keeps V^T rows 16B-aligned

typedef __attribute__((ext_vector_type(8))) short bf16x8;
typedef __attribute__((ext_vector_type(4))) float f32x4;
typedef __attribute__((ext_vector_type(4))) short s16x4;

#define VMCNT(n) asm volatile("s_waitcnt vmcnt(" #n ")" ::: "memory")
#define LGKMCNT0 asm volatile("s_waitcnt lgkmcnt(0)" ::: "memory")

__device__ __forceinline__ short f2bf_rne(float f) {
    union { float f; uint32_t u; } c; c.f = f;
    uint32_t u = c.u + 0x7fffu + ((c.u >> 16) & 1u);
    return (short)(u >> 16);
}

__device__ __forceinline__ int cvt_pk_bf16(float lo, float hi) {
    int r;
    asm("v_cvt_pk_bf16_f32 %0, %1, %2" : "=v"(r) : "v"(lo), "v"(hi));
    return r;
}

__device__ __forceinline__ void gload_lds16(const void* g, void* l) {
    __builtin_amdgcn_global_load_lds(
        (const __attribute__((address_space(1))) void*)g,
        (__attribute__((address_space(3))) void*)l, 16, 0, 0);
}

// T1: XCD-chunked bijective swizzle (m204).
__device__ __forceinline__ int xcd_chunk_swizzle(int orig, int nwg) {
    int q = nwg >> 3, r = nwg & 7;
    int xcd = orig & 7, i = orig >> 3;
    int start = (xcd < r) ? xcd * (q + 1) : r * (q + 1) + (xcd - r) * q;
    return start + i;
}

// ---------------- fp32 -> bf16 conversion (merged, one launch) ----------------
__global__ void f2bf3_kernel(const float* __restrict__ a, short* __restrict__ ao, int na4,
                             const float* __restrict__ b, short* __restrict__ bo, int nb4,
                             const float* __restrict__ c, short* __restrict__ co, int nc4) {
    int i = blockIdx.x * blockDim.x + threadIdx.x;
    const float* src; short* dst; int idx;
    if (i < na4) { src = a; dst = ao; idx = i; }
    else if (i < na4 + nb4) { src = b; dst = bo; idx = i - na4; }
    else if (i < na4 + nb4 + nc4) { src = c; dst = co; idx = i - na4 - nb4; }
    else return;
    f32x4 f = ((const f32x4*)src)[idx];
    s16x4 o;
    o[0] = f2bf_rne(f[0]); o[1] = f2bf_rne(f[1]);
    o[2] = f2bf_rne(f[2]); o[3] = f2bf_rne(f[3]);
    ((s16x4*)dst)[idx] = o;
}

// ---------------- QKV GEMM + RoPE epilogue ----------------
// 128M x 256N tile, BK=32, 4 waves (wave-tile 64x128: acc[4][8], 32 MFMA,
// 12 ds_read_b128 per wave per step). 3 LDS buffers (72 KB -> 2 blocks/CU).
// r4 schedule: vmcnt -> barrier -> ds_read frags -> lgkmcnt(0) -> barrier ->
// stage(cur, t+3) -> MFMA. 6 gload/thread/tile => steady VMCNT(12).
// LDS block-swizzle: stored block g = b ^ (row&3) ^ ((row>>2)&1) (G21: inverse
// applied on global source; reads use matching xor).
__global__ __launch_bounds__(256, 2) void qkv_gemm_kernel(
    const short* __restrict__ xb, const short* __restrict__ wb,
    const float* __restrict__ fcos, const float* __restrict__ fsin,
    short* __restrict__ Qb, short* __restrict__ Kb, short* __restrict__ VTb)
{
    __shared__ short Alds[3][128 * 32];
    __shared__ short Blds[3][256 * 32];
    const int tid = threadIdx.x;
    const int lane = tid & 63, w = tid >> 6;
    const int wm = w >> 1, wn = w & 1;          // 2x2 wave grid, wave-tile 64Mx128N
    const int lr = lane & 15, lg = lane >> 4;
    const int tile = xcd_chunk_swizzle(blockIdx.x, 129 * 9);
    const int mt = tile / 9, nt = tile - (tile / 9) * 9;

    // staging: A slots ca in [0,512): row=ca>>2, blk=ca&3 (2/thread)
    //          B slots cb in [0,1024): row=cb>>2, blk=cb&3 (4/thread)
    const int ca0 = tid, ca1 = tid + 256;
    int ra0 = mt * 128 + (ca0 >> 2); if (ra0 > M_ROWS - 1) ra0 = M_ROWS - 1;
    int ra1 = mt * 128 + (ca1 >> 2); if (ra1 > M_ROWS - 1) ra1 = M_ROWS - 1;
    const int ga0 = (ca0 & 3) ^ ((ca0 >> 2) & 3) ^ ((ca0 >> 4) & 1);
    const int ga1 = (ca1 & 3) ^ ((ca1 >> 2) & 3) ^ ((ca1 >> 4) & 1);
    const short* gA0 = xb + (size_t)ra0 * DIM + ga0 * 8;
    const short* gA1 = xb + (size_t)ra1 * DIM + ga1 * 8;
    short* lA0 = &Alds[0][0] + ca0 * 8;
    short* lA1 = &Alds[0][0] + ca1 * 8;

    const short* gB[4]; short* lB[4];
#pragma unroll
    for (int i = 0; i < 4; i++) {
        int cb = tid + 256 * i;
        int gb = (cb & 3) ^ ((cb >> 2) & 3) ^ ((cb >> 4) & 1);
        gB[i] = wb + (size_t)(nt * 256 + (cb >> 2)) * DIM + gb * 8;   // < 2304
        lB[i] = &Blds[0][0] + cb * 8;
    }

    auto stage = [&](int buf, int kt) {
        const int ko = kt * 32;
        gload_lds16(gA0 + ko, lA0 + buf * (128 * 32));
        gload_lds16(gA1 + ko, lA1 + buf * (128 * 32));
#pragma unroll
        for (int i = 0; i < 4; i++)
            gload_lds16(gB[i] + ko, lB[i] + buf * (256 * 32));
    };

    f32x4 acc[4][8];
#pragma unroll
    for (int i = 0; i < 4; i++)
#pragma unroll
        for (int j = 0; j < 8; j++) acc[i][j] = (f32x4)0.0f;

    stage(0, 0); stage(1, 1); stage(2, 2);

    const int ablk = (lg ^ (lr & 3) ^ ((lr >> 2) & 1)) * 8;   // read-side swizzle

    int cur = 0;
    for (int t = 0; t < 24; ++t) {
        if (t <= 21) { VMCNT(12); } else if (t == 22) { VMCNT(6); } else { VMCNT(0); }
        __builtin_amdgcn_s_barrier();   // tile t confirmed resident by all waves

        bf16x8 af[4], bF[8];
        const short* Ab = &Alds[0][0] + cur * (128 * 32);
        const short* Bb = &Blds[0][0] + cur * (256 * 32);
#pragma unroll
        for (int mi = 0; mi < 4; mi++)
            af[mi] = *(const bf16x8*)&Ab[(wm * 64 + mi * 16 + lr) * 32 + ablk];
#pragma unroll
        for (int ni = 0; ni < 8; ni++)
            bF[ni] = *(const bf16x8*)&Bb[(wn * 128 + ni * 16 + lr) * 32 + ablk];

        if (t <= 20) {
            LGKMCNT0;                        // my reads of buf[cur] complete
            __builtin_amdgcn_s_barrier();    // everyone's reads complete
            stage(cur, t + 3);               // overwrite freed buffer; MFMA hides it
        }

#pragma unroll
        for (int mi = 0; mi < 4; mi++)
#pragma unroll
            for (int ni = 0; ni < 8; ni++)
                acc[mi][ni] = __builtin_amdgcn_mfma_f32_16x16x32_bf16(af[mi], bF[ni], acc[mi][ni], 0, 0, 0);

        cur = (cur == 2) ? 0 : cur + 1;
    }

    // epilogue: RoPE (pairs are adjacent cols = lane^1), scale Q, scatter
#pragma unroll
    for (int mi = 0; mi < 4; mi++) {
        int mbase = mt * 128 + wm * 64 + mi * 16 + lg * 4;
#pragma unroll
        for (int j = 0; j < 4; j++) {
            int m = mbase + j;
            bool valid = (m < M_ROWS);
            int mm = valid ? m : 0;
            int b = mm / SEQ;
            int n = mm - b * SEQ;
#pragma unroll
            for (int ni = 0; ni < 8; ni++) {
                int e = nt * 256 + wn * 128 + ni * 16 + lr;
                int qkv = e / DIM;
                int rem = e - qkv * DIM;
                int h = rem >> 6, d = rem & 63;
                float v = acc[mi][ni][j];
                float vo = __shfl_xor(v, 1);       // partner col e^1 (uniform exec)
                float outv = v;
                if (qkv < 2 && n > 0) {
                    float cs = fcos[(n - 1) * 32 + (d >> 1)];
                    float sn = fsin[(n - 1) * 32 + (d >> 1)];
                    outv = (d & 1) ? (vo * sn + v * cs) : (v * cs - vo * sn);
                }
                if (qkv == 0) outv *= 0.180336881f;   // 1/sqrt(64) * log2(e)
                if (valid) {
                    short bv = f2bf_rne(outv);
                    size_t bh = (size_t)b * NH + h;
                    if (qkv == 0)      Qb[(bh * SEQ + n) * HD64 + d] = bv;
                    else if (qkv == 1) Kb[(bh * SEQ + n) * HD64 + d] = bv;
                    else               VTb[(bh * HD64 + d) * NPAD + n] = bv;
                }
            }
        }
    }
}

// ---------------- flash attention ----------------
// (swapped QK^T, in-register softmax, dbuf K/V, T13 defer-max, T5 setprio)
__global__ __launch_bounds__(256) void attn_kernel(
    const short* __restrict__ Qb, const short* __restrict__ Kb,
    const short* __restrict__ VTb, short* __restrict__ AO)
{
    __shared__ short Klds[2][64 * 64];
    __shared__ short Vlds[2][64 * 64];
    __shared__ int Plds[4][16 * 32];   // per-wave P exchange: [q=lr][32 key-pair dwords]
    const int tid = threadIdx.x;
    const int lane = tid & 63, w = tid >> 6;
    const int lr = lane & 15, lg = lane >> 4;
    const int tile = xcd_chunk_swizzle(blockIdx.x, 17 * 192);
    const int bh = tile / 17, qt = tile - (tile / 17) * 17;
    const int b = bh / NH, h = bh - b * NH;

    const short* Qp = Qb + (size_t)bh * SEQ * HD64;
    const short* Kp = Kb + (size_t)bh * SEQ * HD64;
    const short* Vp = VTb + (size_t)bh * HD64 * NPAD;

    int qr = qt * 64 + w * 16 + lr; if (qr > SEQ - 1) qr = SEQ - 1;
    bf16x8 qf0 = *(const bf16x8*)&Qp[(size_t)qr * HD64 + 0 + lg * 8];
    bf16x8 qf1 = *(const bf16x8*)&Qp[(size_t)qr * HD64 + 32 + lg * 8];

    float m_i = -1e30f, l_i = 0.f;      // per-lane scalars, q = lr
    f32x4 acc[4];
#pragma unroll
    for (int vt = 0; vt < 4; vt++) acc[vt] = (f32x4)0.0f;

    int* pw = &Plds[w][0];
    const int pswz = (lr & 3) << 3;     // xor-swizzle on key-pair index (bits 3,4)

    auto stageKV = [&](int buf, int t) {
        int k0 = t * 64;
#pragma unroll
        for (int i = 0; i < 2; i++) {
            int c = i * 256 + tid;
            int row = c >> 3, ccd = c & 7;
            int cl = ccd ^ (row & 7);
            int krow = k0 + row; if (krow > SEQ - 1) krow = SEQ - 1;
            gload_lds16(Kp + (size_t)krow * HD64 + cl * 8, &Klds[buf][c * 8]);
            gload_lds16(Vp + (size_t)row * NPAD + k0 + cl * 8, &Vlds[buf][c * 8]);
        }
    };

    stageKV(0, 0);
    asm volatile("s_waitcnt vmcnt(0)" ::: "memory");
    __syncthreads();

    for (int t = 0; t < 17; ++t) {
        int cur = t & 1;
        if (t < 16) stageKV(cur ^ 1, t + 1);   // prefetch next K/V under compute

        // swapped QK^T: s[k16] rows = key = k16*16 + lg*4 + j, col q = lr
        f32x4 s[4];
        __builtin_amdgcn_s_setprio(1);
#pragma unroll
        for (int k16 = 0; k16 < 4; k16++) {
            int krow = k16 * 16 + lr;   // A-frag row this lane LOADS
            bf16x8 kf0 = *(const bf16x8*)&Klds[cur][krow * 64 + ((0 + lg) ^ (krow & 7)) * 8];
            bf16x8 kf1 = *(const bf16x8*)&Klds[cur][krow * 64 + ((4 + lg) ^ (krow & 7)) * 8];
            f32x4 d = (f32x4)0.0f;
            d = __builtin_amdgcn_mfma_f32_16x16x32_bf16(kf0, qf0, d, 0, 0, 0);
            d = __builtin_amdgcn_mfma_f32_16x16x32_bf16(kf1, qf1, d, 0, 0, 0);
            s[k16] = d;
        }
        __builtin_amdgcn_s_setprio(0);
        if (t == 16) {
            // only key 1024 (k16==0, lg==0, j==0) is valid
            s[0][0] = (lg == 0) ? s[0][0] : -1e30f;
            s[0][1] = -1e30f; s[0][2] = -1e30f; s[0][3] = -1e30f;
#pragma unroll
            for (int k16 = 1; k16 < 4; k16++) { s[k16][0] = -1e30f; s[k16][1] = -1e30f; s[k16][2] = -1e30f; s[k16][3] = -1e30f; }
        }

        // local max tree over 16 values
        float a0 = fmaxf(s[0][0], s[0][1]), a1 = fmaxf(s[0][2], s[0][3]);
        float a2 = fmaxf(s[1][0], s[1][1]), a3 = fmaxf(s[1][2], s[1][3]);
        float a4 = fmaxf(s[2][0], s[2][1]), a5 = fmaxf(s[2][2], s[2][3]);
        float a6 = fmaxf(s[3][0], s[3][1]), a7 = fmaxf(s[3][2], s[3][3]);
        float b0 = fmaxf(fmaxf(a0, a1), fmaxf(a2, a3));
        float b1 = fmaxf(fmaxf(a4, a5), fmaxf(a6, a7));
        float pmax = fmaxf(b0, b1);
        pmax = fmaxf(pmax, __shfl_xor(pmax, 16));
        pmax = fmaxf(pmax, __shfl_xor(pmax, 32));

        // defer-max (T13): rescale only if some row grew past threshold (exp2 units)
        if (__any(pmax > m_i + 11.54f)) {
            float mnew = fmaxf(m_i, pmax);
            float sc = exp2f(m_i - mnew);
            m_i = mnew;
            l_i *= sc;
#pragma unroll
            for (int j = 0; j < 4; j++) {
                float scj = __shfl(sc, 4 * lg + j);   // sc for q = 4*lg+j lives at lane q
#pragma unroll
                for (int vt = 0; vt < 4; vt++) acc[vt][j] *= scj;
            }
        }

        // P = exp2(s - m), packed to bf16 pairs, rowsum
#pragma unroll
        for (int k16 = 0; k16 < 4; k16++) {
#pragma unroll
            for (int j = 0; j < 4; j++) s[k16][j] = exp2f(s[k16][j] - m_i);
        }
        float r0 = (s[0][0] + s[0][1]) + (s[0][2] + s[0][3]);
        float r1 = (s[1][0] + s[1][1]) + (s[1][2] + s[1][3]);
        float r2 = (s[2][0] + s[2][1]) + (s[2][2] + s[2][3]);
        float r3 = (s[3][0] + s[3][1]) + (s[3][2] + s[3][3]);
        float rowsum = (r0 + r1) + (r2 + r3);
        rowsum += __shfl_xor(rowsum, 16);
        rowsum += __shfl_xor(rowsum, 32);
        l_i += rowsum;

        // exchange P[key][q] -> A-frag P[q][key] via per-wave swizzled LDS
#pragma unroll
        for (int k16 = 0; k16 < 4; k16++) {
            int pk0 = cvt_pk_bf16(s[k16][0], s[k16][1]);
            int pk1 = cvt_pk_bf16(s[k16][2], s[k16][3]);
            int pbase = 8 * k16 + 2 * lg;
            pw[lr * 32 + ((pbase + 0) ^ pswz)] = pk0;
            pw[lr * 32 + ((pbase + 1) ^ pswz)] = pk1;
        }
        bf16x8 pa0 = *(const bf16x8*)&pw[lr * 32 + ((4 * lg) ^ pswz)];        // keys 0..31
        bf16x8 pa1 = *(const bf16x8*)&pw[lr * 32 + ((16 + 4 * lg) ^ pswz)];   // keys 32..63

        __builtin_amdgcn_s_setprio(1);
#pragma unroll
        for (int vt = 0; vt < 4; vt++) {
            int dr = vt * 16 + lr;
            bf16x8 vf0 = *(const bf16x8*)&Vlds[cur][dr * 64 + ((0 + lg) ^ (dr & 7)) * 8];
            bf16x8 vf1 = *(const bf16x8*)&Vlds[cur][dr * 64 + ((4 + lg) ^ (dr & 7)) * 8];
            acc[vt] = __builtin_amdgcn_mfma_f32_16x16x32_bf16(pa0, vf0, acc[vt], 0, 0, 0);
            acc[vt] = __builtin_amdgcn_mfma_f32_16x16x32_bf16(pa1, vf1, acc[vt], 0, 0, 0);
        }
        __builtin_amdgcn_s_setprio(0);

        asm volatile("s_waitcnt vmcnt(0)" ::: "memory");
        __syncthreads();
    }

    // store attn out: [b*1025+q][h*64 + d] bf16; gather l for q = lg*4+j
    float inv[4];
#pragma unroll
    for (int j = 0; j < 4; j++) inv[j] = 1.0f / __shfl(l_i, 4 * lg + j);
#pragma unroll
    for (int vt = 0; vt < 4; vt++) {
#pragma unroll
        for (int j = 0; j < 4; j++) {
            int qrow = qt * 64 + w * 16 + lg * 4 + j;
            if (qrow < SEQ) {
                AO[((size_t)(b * SEQ + qrow)) * DIM + h * HD64 + vt * 16 + lr] =
                    f2bf_rne(acc[vt][j] * inv[j]);
            }
        }
    }
}

// ---------------- output projection GEMM + bias ----------------
// r4 structure verbatim: 128x128, 4 waves, 3-buf, VMCNT(8), lgkm+barrier2.
__global__ __launch_bounds__(256) void proj_gemm_kernel(
    const short* __restrict__ ab, const short* __restrict__ wb,
    const float* __restrict__ bias, float* __restrict__ out)
{
    __shared__ short Alds[3][128 * 32];
    __shared__ short Blds[3][128 * 32];
    const int tid = threadIdx.x;
    const int lane = tid & 63, w = tid >> 6;
    const int wm = w >> 1, wn = w & 1;
    const int lr = lane & 15, lg = lane >> 4;
    const int tile = xcd_chunk_swizzle(blockIdx.x, 129 * 6);
    const int mt = tile / 6, nt = tile - (tile / 6) * 6;

    const int c0 = tid, c1 = 256 + tid;
    int ra0 = mt * 128 + (c0 >> 2); if (ra0 > M_ROWS - 1) ra0 = M_ROWS - 1;
    int ra1 = mt * 128 + (c1 >> 2); if (ra1 > M_ROWS - 1) ra1 = M_ROWS - 1;
    const short* gA0 = ab + (size_t)ra0 * DIM + (c0 & 3) * 8;
    const short* gA1 = ab + (size_t)ra1 * DIM + (c1 & 3) * 8;
    const short* gB0 = wb + (size_t)(nt * 128 + (c0 >> 2)) * DIM + (c0 & 3) * 8;
    const short* gB1 = wb + (size_t)(nt * 128 + (c1 >> 2)) * DIM + (c1 & 3) * 8;
    short* lA0 = &Alds[0][0] + c0 * 8;
    short* lA1 = &Alds[0][0] + c1 * 8;
    short* lB0 = &Blds[0][0] + c0 * 8;
    short* lB1 = &Blds[0][0] + c1 * 8;

    auto stage = [&](int buf, int kt) {
        const int ko = kt * 32;
        const int lo = buf * (128 * 32);
        gload_lds16(gA0 + ko, lA0 + lo);
        gload_lds16(gA1 + ko, lA1 + lo);
        gload_lds16(gB0 + ko, lB0 + lo);
        gload_lds16(gB1 + ko, lB1 + lo);
    };

    f32x4 acc[4][4];
#pragma unroll
    for (int i = 0; i < 4; i++)
#pragma unroll
        for (int j = 0; j < 4; j++) acc[i][j] = (f32x4)0.0f;

    stage(0, 0); stage(1, 1); stage(2, 2);

    int cur = 0;
    for (int t = 0; t < 24; ++t) {
        if (t <= 21) { VMCNT(8); } else if (t == 22) { VMCNT(4); } else { VMCNT(0); }
        __builtin_amdgcn_s_barrier();

        bf16x8 af[4], bfr[4];
        const short* Ab = &Alds[0][0] + cur * (128 * 32);
        const short* Bb = &Blds[0][0] + cur * (128 * 32);
#pragma unroll
        for (int mi = 0; mi < 4; mi++)
            af[mi] = *(const bf16x8*)&Ab[(wm * 64 + mi * 16 + lr) * 32 + lg * 8];
#pragma unroll
        for (int ni = 0; ni < 4; ni++)
            bfr[ni] = *(const bf16x8*)&Bb[(wn * 64 + ni * 16 + lr) * 32 + lg * 8];

        if (t <= 20) {
            LGKMCNT0;
            __builtin_amdgcn_s_barrier();
            stage(cur, t + 3);
        }

#pragma unroll
        for (int mi = 0; mi < 4; mi++)
#pragma unroll
            for (int ni = 0; ni < 4; ni++)
                acc[mi][ni] = __builtin_amdgcn_mfma_f32_16x16x32_bf16(af[mi], bfr[ni], acc[mi][ni], 0, 0, 0);

        cur = (cur == 2) ? 0 : cur + 1;
    }

#pragma unroll
    for (int ni = 0; ni < 4; ni++) {
        int e = nt * 128 + wn * 64 + ni * 16 + lr;
        float bv = bias[e];
#pragma unroll
        for (int mi = 0; mi < 4; mi++) {
#pragma unroll
            for (int j = 0; j < 4; j++) {
                int m = mt * 128 + wm * 64 + mi * 16 + lg * 4 + j;
                if (m < M_ROWS) out[(size_t)m * DIM + e] = acc[mi][ni][j] + bv;
            }
        }
    }
}

extern "C" void kernel_launch(void* const* d_in, const int* in_sizes, int n_in,
                              void* d_out, int out_size, void* d_ws, size_t ws_size,
                              hipStream_t stream) {
    const float* x     = (const float*)d_in[0];
    const float* fcos  = (const float*)d_in[1];
    const float* fsin  = (const float*)d_in[2];
    const float* wqkv  = (const float*)d_in[3];
    const float* wproj = (const float*)d_in[4];
    const float* bproj = (const float*)d_in[5];
    float* out = (float*)d_out;

    char* ws = (char*)d_ws;
    size_t off = 0;
    auto salloc = [&](size_t bytes) { void* p = ws + off; off += (bytes + 255) & ~(size_t)255; return p; };
    short* xb     = (short*)salloc((size_t)M_ROWS * DIM * 2);
    short* wqkvb  = (short*)salloc((size_t)2304 * DIM * 2);
    short* wprojb = (short*)salloc((size_t)DIM * DIM * 2);
    short* Qb     = (short*)salloc((size_t)192 * SEQ * HD64 * 2);
    short* Kb     = (short*)salloc((size_t)192 * SEQ * HD64 * 2);
    short* VTb    = (short*)salloc((size_t)192 * HD64 * NPAD * 2);
    short* AO     = (short*)salloc((size_t)M_ROWS * DIM * 2);

    {
        int na4 = M_ROWS * DIM / 4;      // 3,148,800
        int nb4 = 2304 * DIM / 4;        //   442,368
        int nc4 = DIM * DIM / 4;         //   147,456
        int tot = na4 + nb4 + nc4;
        f2bf3_kernel<<<(tot + 255) / 256, 256, 0, stream>>>(x, xb, na4, wqkv, wqkvb, nb4, wproj, wprojb, nc4);
    }

    qkv_gemm_kernel<<<129 * 9, 256, 0, stream>>>(xb, wqkvb, fcos, fsin, Qb, Kb, VTb);
    attn_kernel<<<17 * 192, 256, 0, stream>>>(Qb, Kb, VTb, AO);
    proj_gemm_kernel<<<129 * 6, 256, 0, stream>>>(AO, wprojb, bproj, out);
}

// Round 9
// 340.305 us; speedup vs baseline: 1.1143x; 1.0300x over previous
//
#include <hip/hip_runtime.h>
#include <stdint.h>

#define NH 12
#define HD64 64
#define SEQ 1025
#define M_ROWS (16 * SEQ)   // 16400
#define DIM 768
#define NPAD 1088           // 17 * 64, keeps V^T rows 16B-aligned
#define NT 12               // K-tiles of 64

typedef __attribute__((ext_vector_type(8))) short bf16x8;
typedef __attribute__((ext_vector_type(4))) float f32x4;
typedef __attribute__((ext_vector_type(4))) short s16x4;

#define VMCNT(n) asm volatile("s_waitcnt vmcnt(" #n ")" ::: "memory")
#define SBAR     asm volatile("s_barrier" ::: "memory")

__device__ __forceinline__ short f2bf_rne(float f) {
    union { float f; uint32_t u; } c; c.f = f;
    uint32_t u = c.u + 0x7fffu + ((c.u >> 16) & 1u);
    return (short)(u >> 16);
}

__device__ __forceinline__ int cvt_pk_bf16(float lo, float hi) {
    int r;
    asm("v_cvt_pk_bf16_f32 %0, %1, %2" : "=v"(r) : "v"(lo), "v"(hi));
    return r;
}

__device__ __forceinline__ void gload_lds16(const void* g, void* l) {
    __builtin_amdgcn_global_load_lds(
        (const __attribute__((address_space(1))) void*)g,
        (__attribute__((address_space(3))) void*)l, 16, 0, 0);
}

// T1: XCD-chunked bijective swizzle (m204).
__device__ __forceinline__ int xcd_chunk_swizzle(int orig, int nwg) {
    int q = nwg >> 3, r = nwg & 7;
    int xcd = orig & 7, i = orig >> 3;
    int start = (xcd < r) ? xcd * (q + 1) : r * (q + 1) + (xcd - r) * q;
    return start + i;
}

// ---------------- fp32 -> bf16 conversion (merged, one launch) ----------------
__global__ void f2bf3_kernel(const float* __restrict__ a, short* __restrict__ ao, int na4,
                             const float* __restrict__ b, short* __restrict__ bo, int nb4,
                             const float* __restrict__ c, short* __restrict__ co, int nc4) {
    int i = blockIdx.x * blockDim.x + threadIdx.x;
    const float* src; short* dst; int idx;
    if (i < na4) { src = a; dst = ao; idx = i; }
    else if (i < na4 + nb4) { src = b; dst = bo; idx = i - na4; }
    else if (i < na4 + nb4 + nc4) { src = c; dst = co; idx = i - na4 - nb4; }
    else return;
    f32x4 f = ((const f32x4*)src)[idx];
    s16x4 o;
    o[0] = f2bf_rne(f[0]); o[1] = f2bf_rne(f[1]);
    o[2] = f2bf_rne(f[2]); o[3] = f2bf_rne(f[3]);
    ((s16x4*)dst)[idx] = o;
}

// ================= 256x256 8-phase GEMM core (m201 template port) =============
// 8 waves (2M x 4N), wave-tile 128x64, BK=64 as 2 K-halves of 32.
// LDS [2 buf][A,B][kh][256 rows x 32 k] = 128 KiB. 4 phases per K-tile.
// RACE FIX (r8): the counted vmcnt confirming a half executes ONE PHASE BEFORE
// its first ds_read, followed by a barrier (memory-fenced s_barrier):
//   ph(0,0): read A0/B0 (confirmed @ t-1 ph(1,1)); stage A0(t+1)
//   ph(0,1): read A0-hi;                            stage B0(t+1); vmcnt(4)->t:kh1
//   ph(1,0): read A1/B1 (just confirmed);           stage A1(t+1)
//   ph(1,1): read A1-hi;                            stage B1(t+1); vmcnt(4)->t+1:kh0
// Ledger (2 loads/half/thread): at each counted wait exactly 8 outstanding,
// drain to 4 = oldest half pair. Never 0 until the tail.
// LDS swizzle: physical k-block = logical ^ ((row>>1)&3); reads use
// kbp = lg ^ ((lr>>1)&3); worst 2-way = free (m136). Inverse on global src (G21).

#define HALF_SH 8192   // shorts per half buffer (256*32)

#define GEMM_PH(kh, mh, Ab, Bb, DO_B, STG, CNT)                                   \
        {                                                                          \
            if (DO_B) {                                                            \
                _Pragma("unroll")                                                  \
                for (int ni = 0; ni < 4; ni++)                                     \
                    b[ni] = *(const bf16x8*)&Bb[(wn * 64 + ni * 16 + lr) * 32 + kbp]; \
            }                                                                      \
            _Pragma("unroll")                                                      \
            for (int mi = 0; mi < 4; mi++)                                         \
                a[mi] = *(const bf16x8*)&Ab[(wm * 128 + (mh) * 64 + mi * 16 + lr) * 32 + kbp]; \
            STG;                                                                   \
            CNT;                                                                   \
            SBAR;                                                                  \
            __builtin_amdgcn_s_setprio(1);                                         \
            _Pragma("unroll")                                                      \
            for (int mi = 0; mi < 4; mi++)                                         \
                _Pragma("unroll")                                                  \
                for (int ni = 0; ni < 4; ni++)                                     \
                    acc[(mh) * 4 + mi][ni] = __builtin_amdgcn_mfma_f32_16x16x32_bf16( \
                        a[mi], b[ni], acc[(mh) * 4 + mi][ni], 0, 0, 0);            \
            __builtin_amdgcn_s_setprio(0);                                         \
            SBAR;                                                                  \
        }

// ---------------- QKV GEMM + RoPE epilogue ----------------
__global__ __launch_bounds__(512, 1) void qkv_gemm_kernel(
    const short* __restrict__ xb, const short* __restrict__ wb,
    const float* __restrict__ fcos, const float* __restrict__ fsin,
    short* __restrict__ Qb, short* __restrict__ Kb, short* __restrict__ VTb)
{
    __shared__ short L[2 * 2 * 2 * HALF_SH];
    const int tid = threadIdx.x;
    const int lane = tid & 63, w = tid >> 6;
    const int wm = w >> 2, wn = w & 3;          // 2M x 4N waves
    const int lr = lane & 15, lg = lane >> 4;
    const int tile = xcd_chunk_swizzle(blockIdx.x, 65 * 9);
    const int mt = tile / 9, nt = tile - (tile / 9) * 9;
    const int kbp = (lg ^ ((lr >> 1) & 3)) * 8;  // swizzled k-block (shorts)

    int s_r[2], s_kb[2];
#pragma unroll
    for (int i = 0; i < 2; i++) {
        int slot = tid + i * 512;
        s_r[i] = slot >> 2;
        s_kb[i] = ((slot & 3) ^ ((s_r[i] >> 1) & 3)) * 8;
    }
    const short* asrc[2]; const short* bsrc[2];
#pragma unroll
    for (int i = 0; i < 2; i++) {
        int ra = mt * 256 + s_r[i]; if (ra > M_ROWS - 1) ra = M_ROWS - 1;
        asrc[i] = xb + (size_t)ra * DIM + s_kb[i];
        bsrc[i] = wb + (size_t)(nt * 256 + s_r[i]) * DIM + s_kb[i];   // < 2304
    }

    auto stageA = [&](int buf, int kh, int kt) {
#pragma unroll
        for (int i = 0; i < 2; i++)
            gload_lds16(asrc[i] + kt * 64 + kh * 32,
                        &L[((buf * 2 + 0) * 2 + kh) * HALF_SH + (tid + i * 512) * 8]);
    };
    auto stageB = [&](int buf, int kh, int kt) {
#pragma unroll
        for (int i = 0; i < 2; i++)
            gload_lds16(bsrc[i] + kt * 64 + kh * 32,
                        &L[((buf * 2 + 1) * 2 + kh) * HALF_SH + (tid + i * 512) * 8]);
    };

    f32x4 acc[8][4];
#pragma unroll
    for (int i = 0; i < 8; i++)
#pragma unroll
        for (int j = 0; j < 4; j++) acc[i][j] = (f32x4)0.0f;

    // prologue: tile 0 (A0,B0,A1,B1), then confirm kh0 before first read
    stageA(0, 0, 0); stageB(0, 0, 0); stageA(0, 1, 0); stageB(0, 1, 0);
    VMCNT(4);
    SBAR;

    for (int t = 0; t < NT; ++t) {
        const int bf = t & 1;
        const bool st = (t + 1 < NT);
        const short* Ab0 = &L[((bf * 2 + 0) * 2 + 0) * HALF_SH];
        const short* Ab1 = &L[((bf * 2 + 0) * 2 + 1) * HALF_SH];
        const short* Bb0 = &L[((bf * 2 + 1) * 2 + 0) * HALF_SH];
        const short* Bb1 = &L[((bf * 2 + 1) * 2 + 1) * HALF_SH];
        bf16x8 a[4], b[4];

        GEMM_PH(0, 0, Ab0, Bb0, true,  if (st) stageA(bf ^ 1, 0, t + 1), ((void)0))
        GEMM_PH(0, 1, Ab0, Bb0, false, if (st) stageB(bf ^ 1, 0, t + 1),
                if (st) { VMCNT(4); } else { VMCNT(0); })
        GEMM_PH(1, 0, Ab1, Bb1, true,  if (st) stageA(bf ^ 1, 1, t + 1), ((void)0))
        GEMM_PH(1, 1, Ab1, Bb1, false, if (st) stageB(bf ^ 1, 1, t + 1),
                if (st) { VMCNT(4); })
    }

    // epilogue: wave-uniform (qkv, h); RoPE pairs are adjacent cols = lane^1
    const int ebase = nt * 256 + wn * 64;
    const int qkvi = ebase / DIM;
    const int h = (ebase - qkvi * DIM) >> 6;
    const float qscale = (qkvi == 0) ? 0.180336881f : 1.0f;   // 1/8 * log2(e)
#pragma unroll
    for (int mi = 0; mi < 8; mi++) {
        int mbase = mt * 256 + wm * 128 + mi * 16 + lg * 4;
#pragma unroll
        for (int j = 0; j < 4; j++) {
            int m = mbase + j;
            bool valid = (m < M_ROWS);
            int mm = valid ? m : 0;
            int b2 = mm / SEQ;
            int n = mm - b2 * SEQ;
            size_t bh = (size_t)b2 * NH + h;
#pragma unroll
            for (int ni = 0; ni < 4; ni++) {
                int d = ni * 16 + lr;
                float v = acc[mi][ni][j];
                float vo = __shfl_xor(v, 1);
                float outv = v;
                if (qkvi < 2 && n > 0) {
                    float cs = fcos[(n - 1) * 32 + ni * 8 + (lr >> 1)];
                    float sn = fsin[(n - 1) * 32 + ni * 8 + (lr >> 1)];
                    outv = (d & 1) ? (vo * sn + v * cs) : (v * cs - vo * sn);
                }
                outv *= qscale;
                if (valid) {
                    short bv = f2bf_rne(outv);
                    if (qkvi == 0)      Qb[(bh * SEQ + n) * HD64 + d] = bv;
                    else if (qkvi == 1) Kb[(bh * SEQ + n) * HD64 + d] = bv;
                    else                VTb[(bh * HD64 + d) * NPAD + n] = bv;
                }
            }
        }
    }
}

// ---------------- output projection GEMM + bias (same fixed 8-phase core) ----
__global__ __launch_bounds__(512, 1) void proj_gemm_kernel(
    const short* __restrict__ ab, const short* __restrict__ wb,
    const float* __restrict__ bias, float* __restrict__ out)
{
    __shared__ short L[2 * 2 * 2 * HALF_SH];
    const int tid = threadIdx.x;
    const int lane = tid & 63, w = tid >> 6;
    const int wm = w >> 2, wn = w & 3;
    const int lr = lane & 15, lg = lane >> 4;
    const int tile = xcd_chunk_swizzle(blockIdx.x, 65 * 3);
    const int mt = tile / 3, nt = tile - (tile / 3) * 3;
    const int kbp = (lg ^ ((lr >> 1) & 3)) * 8;

    int s_r[2], s_kb[2];
#pragma unroll
    for (int i = 0; i < 2; i++) {
        int slot = tid + i * 512;
        s_r[i] = slot >> 2;
        s_kb[i] = ((slot & 3) ^ ((s_r[i] >> 1) & 3)) * 8;
    }
    const short* asrc[2]; const short* bsrc[2];
#pragma unroll
    for (int i = 0; i < 2; i++) {
        int ra = mt * 256 + s_r[i]; if (ra > M_ROWS - 1) ra = M_ROWS - 1;
        asrc[i] = ab + (size_t)ra * DIM + s_kb[i];
        bsrc[i] = wb + (size_t)(nt * 256 + s_r[i]) * DIM + s_kb[i];   // < 768
    }

    auto stageA = [&](int buf, int kh, int kt) {
#pragma unroll
        for (int i = 0; i < 2; i++)
            gload_lds16(asrc[i] + kt * 64 + kh * 32,
                        &L[((buf * 2 + 0) * 2 + kh) * HALF_SH + (tid + i * 512) * 8]);
    };
    auto stageB = [&](int buf, int kh, int kt) {
#pragma unroll
        for (int i = 0; i < 2; i++)
            gload_lds16(bsrc[i] + kt * 64 + kh * 32,
                        &L[((buf * 2 + 1) * 2 + kh) * HALF_SH + (tid + i * 512) * 8]);
    };

    f32x4 acc[8][4];
#pragma unroll
    for (int i = 0; i < 8; i++)
#pragma unroll
        for (int j = 0; j < 4; j++) acc[i][j] = (f32x4)0.0f;

    stageA(0, 0, 0); stageB(0, 0, 0); stageA(0, 1, 0); stageB(0, 1, 0);
    VMCNT(4);
    SBAR;

    for (int t = 0; t < NT; ++t) {
        const int bf = t & 1;
        const bool st = (t + 1 < NT);
        const short* Ab0 = &L[((bf * 2 + 0) * 2 + 0) * HALF_SH];
        const short* Ab1 = &L[((bf * 2 + 0) * 2 + 1) * HALF_SH];
        const short* Bb0 = &L[((bf * 2 + 1) * 2 + 0) * HALF_SH];
        const short* Bb1 = &L[((bf * 2 + 1) * 2 + 1) * HALF_SH];
        bf16x8 a[4], b[4];

        GEMM_PH(0, 0, Ab0, Bb0, true,  if (st) stageA(bf ^ 1, 0, t + 1), ((void)0))
        GEMM_PH(0, 1, Ab0, Bb0, false, if (st) stageB(bf ^ 1, 0, t + 1),
                if (st) { VMCNT(4); } else { VMCNT(0); })
        GEMM_PH(1, 0, Ab1, Bb1, true,  if (st) stageA(bf ^ 1, 1, t + 1), ((void)0))
        GEMM_PH(1, 1, Ab1, Bb1, false, if (st) stageB(bf ^ 1, 1, t + 1),
                if (st) { VMCNT(4); })
    }

#pragma unroll
    for (int ni = 0; ni < 4; ni++) {
        int e = nt * 256 + wn * 64 + ni * 16 + lr;
        float bv = bias[e];
#pragma unroll
        for (int mi = 0; mi < 8; mi++) {
#pragma unroll
            for (int j = 0; j < 4; j++) {
                int m = mt * 256 + wm * 128 + mi * 16 + lg * 4 + j;
                if (m < M_ROWS) out[(size_t)m * DIM + e] = acc[mi][ni][j] + bv;
            }
        }
    }
}

// ---------------- flash attention ----------------
// (unchanged: swapped QK^T, in-register softmax, dbuf K/V, T13 defer-max, T5)
__global__ __launch_bounds__(256) void attn_kernel(
    const short* __restrict__ Qb, const short* __restrict__ Kb,
    const short* __restrict__ VTb, short* __restrict__ AO)
{
    __shared__ short Klds[2][64 * 64];
    __shared__ short Vlds[2][64 * 64];
    __shared__ int Plds[4][16 * 32];
    const int tid = threadIdx.x;
    const int lane = tid & 63, w = tid >> 6;
    const int lr = lane & 15, lg = lane >> 4;
    const int tile = xcd_chunk_swizzle(blockIdx.x, 17 * 192);
    const int bh = tile / 17, qt = tile - (tile / 17) * 17;
    const int b = bh / NH, h = bh - b * NH;

    const short* Qp = Qb + (size_t)bh * SEQ * HD64;
    const short* Kp = Kb + (size_t)bh * SEQ * HD64;
    const short* Vp = VTb + (size_t)bh * HD64 * NPAD;

    int qr = qt * 64 + w * 16 + lr; if (qr > SEQ - 1) qr = SEQ - 1;
    bf16x8 qf0 = *(const bf16x8*)&Qp[(size_t)qr * HD64 + 0 + lg * 8];
    bf16x8 qf1 = *(const bf16x8*)&Qp[(size_t)qr * HD64 + 32 + lg * 8];

    float m_i = -1e30f, l_i = 0.f;
    f32x4 acc[4];
#pragma unroll
    for (int vt = 0; vt < 4; vt++) acc[vt] = (f32x4)0.0f;

    int* pw = &Plds[w][0];
    const int pswz = (lr & 3) << 3;

    auto stageKV = [&](int buf, int t) {
        int k0 = t * 64;
#pragma unroll
        for (int i = 0; i < 2; i++) {
            int c = i * 256 + tid;
            int row = c >> 3, ccd = c & 7;
            int cl = ccd ^ (row & 7);
            int krow = k0 + row; if (krow > SEQ - 1) krow = SEQ - 1;
            gload_lds16(Kp + (size_t)krow * HD64 + cl * 8, &Klds[buf][c * 8]);
            gload_lds16(Vp + (size_t)row * NPAD + k0 + cl * 8, &Vlds[buf][c * 8]);
        }
    };

    stageKV(0, 0);
    asm volatile("s_waitcnt vmcnt(0)" ::: "memory");
    __syncthreads();

    for (int t = 0; t < 17; ++t) {
        int cur = t & 1;
        if (t < 16) stageKV(cur ^ 1, t + 1);

        f32x4 s[4];
        __builtin_amdgcn_s_setprio(1);
#pragma unroll
        for (int k16 = 0; k16 < 4; k16++) {
            int krow = k16 * 16 + lr;
            bf16x8 kf0 = *(const bf16x8*)&Klds[cur][krow * 64 + ((0 + lg) ^ (krow & 7)) * 8];
            bf16x8 kf1 = *(const bf16x8*)&Klds[cur][krow * 64 + ((4 + lg) ^ (krow & 7)) * 8];
            f32x4 d = (f32x4)0.0f;
            d = __builtin_amdgcn_mfma_f32_16x16x32_bf16(kf0, qf0, d, 0, 0, 0);
            d = __builtin_amdgcn_mfma_f32_16x16x32_bf16(kf1, qf1, d, 0, 0, 0);
            s[k16] = d;
        }
        __builtin_amdgcn_s_setprio(0);
        if (t == 16) {
            s[0][0] = (lg == 0) ? s[0][0] : -1e30f;
            s[0][1] = -1e30f; s[0][2] = -1e30f; s[0][3] = -1e30f;
#pragma unroll
            for (int k16 = 1; k16 < 4; k16++) { s[k16][0] = -1e30f; s[k16][1] = -1e30f; s[k16][2] = -1e30f; s[k16][3] = -1e30f; }
        }

        float a0 = fmaxf(s[0][0], s[0][1]), a1 = fmaxf(s[0][2], s[0][3]);
        float a2 = fmaxf(s[1][0], s[1][1]), a3 = fmaxf(s[1][2], s[1][3]);
        float a4 = fmaxf(s[2][0], s[2][1]), a5 = fmaxf(s[2][2], s[2][3]);
        float a6 = fmaxf(s[3][0], s[3][1]), a7 = fmaxf(s[3][2], s[3][3]);
        float b0 = fmaxf(fmaxf(a0, a1), fmaxf(a2, a3));
        float b1 = fmaxf(fmaxf(a4, a5), fmaxf(a6, a7));
        float pmax = fmaxf(b0, b1);
        pmax = fmaxf(pmax, __shfl_xor(pmax, 16));
        pmax = fmaxf(pmax, __shfl_xor(pmax, 32));

        if (__any(pmax > m_i + 11.54f)) {
            float mnew = fmaxf(m_i, pmax);
            float sc = exp2f(m_i - mnew);
            m_i = mnew;
            l_i *= sc;
#pragma unroll
            for (int j = 0; j < 4; j++) {
                float scj = __shfl(sc, 4 * lg + j);
#pragma unroll
                for (int vt = 0; vt < 4; vt++) acc[vt][j] *= scj;
            }
        }

#pragma unroll
        for (int k16 = 0; k16 < 4; k16++) {
#pragma unroll
            for (int j = 0; j < 4; j++) s[k16][j] = exp2f(s[k16][j] - m_i);
        }
        float r0 = (s[0][0] + s[0][1]) + (s[0][2] + s[0][3]);
        float r1 = (s[1][0] + s[1][1]) + (s[1][2] + s[1][3]);
        float r2 = (s[2][0] + s[2][1]) + (s[2][2] + s[2][3]);
        float r3 = (s[3][0] + s[3][1]) + (s[3][2] + s[3][3]);
        float rowsum = (r0 + r1) + (r2 + r3);
        rowsum += __shfl_xor(rowsum, 16);
        rowsum += __shfl_xor(rowsum, 32);
        l_i += rowsum;

#pragma unroll
        for (int k16 = 0; k16 < 4; k16++) {
            int pk0 = cvt_pk_bf16(s[k16][0], s[k16][1]);
            int pk1 = cvt_pk_bf16(s[k16][2], s[k16][3]);
            int pbase = 8 * k16 + 2 * lg;
            pw[lr * 32 + ((pbase + 0) ^ pswz)] = pk0;
            pw[lr * 32 + ((pbase + 1) ^ pswz)] = pk1;
        }
        bf16x8 pa0 = *(const bf16x8*)&pw[lr * 32 + ((4 * lg) ^ pswz)];
        bf16x8 pa1 = *(const bf16x8*)&pw[lr * 32 + ((16 + 4 * lg) ^ pswz)];

        __builtin_amdgcn_s_setprio(1);
#pragma unroll
        for (int vt = 0; vt < 4; vt++) {
            int dr = vt * 16 + lr;
            bf16x8 vf0 = *(const bf16x8*)&Vlds[cur][dr * 64 + ((0 + lg) ^ (dr & 7)) * 8];
            bf16x8 vf1 = *(const bf16x8*)&Vlds[cur][dr * 64 + ((4 + lg) ^ (dr & 7)) * 8];
            acc[vt] = __builtin_amdgcn_mfma_f32_16x16x32_bf16(pa0, vf0, acc[vt], 0, 0, 0);
            acc[vt] = __builtin_amdgcn_mfma_f32_16x16x32_bf16(pa1, vf1, acc[vt], 0, 0, 0);
        }
        __builtin_amdgcn_s_setprio(0);

        asm volatile("s_waitcnt vmcnt(0)" ::: "memory");
        __syncthreads();
    }

    float inv[4];
#pragma unroll
    for (int j = 0; j < 4; j++) inv[j] = 1.0f / __shfl(l_i, 4 * lg + j);
#pragma unroll
    for (int vt = 0; vt < 4; vt++) {
#pragma unroll
        for (int j = 0; j < 4; j++) {
            int qrow = qt * 64 + w * 16 + lg * 4 + j;
            if (qrow < SEQ) {
                AO[((size_t)(b * SEQ + qrow)) * DIM + h * HD64 + vt * 16 + lr] =
                    f2bf_rne(acc[vt][j] * inv[j]);
            }
        }
    }
}

extern "C" void kernel_launch(void* const* d_in, const int* in_sizes, int n_in,
                              void* d_out, int out_size, void* d_ws, size_t ws_size,
                              hipStream_t stream) {
    const float* x     = (const float*)d_in[0];
    const float* fcos  = (const float*)d_in[1];
    const float* fsin  = (const float*)d_in[2];
    const float* wqkv  = (const float*)d_in[3];
    const float* wproj = (const float*)d_in[4];
    const float* bproj = (const float*)d_in[5];
    float* out = (float*)d_out;

    char* ws = (char*)d_ws;
    size_t off = 0;
    auto salloc = [&](size_t bytes) { void* p = ws + off; off += (bytes + 255) & ~(size_t)255; return p; };
    short* xb     = (short*)salloc((size_t)M_ROWS * DIM * 2);
    short* wqkvb  = (short*)salloc((size_t)2304 * DIM * 2);
    short* wprojb = (short*)salloc((size_t)DIM * DIM * 2);
    short* Qb     = (short*)salloc((size_t)192 * SEQ * HD64 * 2);
    short* Kb     = (short*)salloc((size_t)192 * SEQ * HD64 * 2);
    short* VTb    = (short*)salloc((size_t)192 * HD64 * NPAD * 2);
    short* AO     = (short*)salloc((size_t)M_ROWS * DIM * 2);

    {
        int na4 = M_ROWS * DIM / 4;
        int nb4 = 2304 * DIM / 4;
        int nc4 = DIM * DIM / 4;
        int tot = na4 + nb4 + nc4;
        f2bf3_kernel<<<(tot + 255) / 256, 256, 0, stream>>>(x, xb, na4, wqkv, wqkvb, nb4, wproj, wprojb, nc4);
    }

    qkv_gemm_kernel<<<65 * 9, 512, 0, stream>>>(xb, wqkvb, fcos, fsin, Qb, Kb, VTb);
    attn_kernel<<<17 * 192, 256, 0, stream>>>(Qb, Kb, VTb, AO);
    proj_gemm_kernel<<<65 * 3, 512, 0, stream>>>(AO, wprojb, bproj, out);
}